// Round 4
// baseline (529.622 us; speedup 1.0000x reference)
//
#include <hip/hip_runtime.h>
#include <hip/hip_bf16.h>

// ---------------------------------------------------------------------------
// Feature_Decoder: out = LN(leaky_relu(inp @ Wf^T + bf) * (static @ Wc^T + bc))
// B=32, N=2048, F=512, K_city=256, D=1024.  M = B*N = 65536.
//   k1 convw: W_feat fp32 -> bf16 in MFMA-slab order Wr[kb][1024 rows][32 k]
//   k2 city : c = static @ Wc^T + bc, MFMA bf16, store bf16 (ws, 4 MB)
//   k3 feat : 64-row x full-D block, 1024 thr = 16 waves, wave = 64x64 tile.
//             m97-structure K-loop (BK=32, 16 steps): BOTH operands staged
//             via global_load_lds into double-buffered LDS (A fp32 8KB
//             XOR-swizzled via pre-swizzled global source; B bf16 64KB
//             linear slab), one barrier per step. A converted fp32->bf16
//             at frag-read with v_cvt_pk_bf16_f32. Fused LN epilogue.
//   (Resubmission of round-3 source: bench failed on infra, not kernel.)
// ---------------------------------------------------------------------------

typedef __attribute__((ext_vector_type(8))) short short8;
typedef __attribute__((ext_vector_type(4))) float f32x4;

__device__ __forceinline__ unsigned short f2bf(float f) {
    unsigned int u = __float_as_uint(f);
    return (unsigned short)((u + 0x7FFFu + ((u >> 16) & 1u)) >> 16);   // RNE
}
__device__ __forceinline__ float b2f(unsigned short h) {
    return __uint_as_float(((unsigned int)h) << 16);
}

#define LDS_ASYNC16(g, l) __builtin_amdgcn_global_load_lds(                 \
    (const __attribute__((address_space(1))) void*)(g),                     \
    (__attribute__((address_space(3))) void*)(l), 16, 0, 0)

// ---------------------------------------------------------------------------
// k1: W_feat [1024,512] fp32 -> bf16, scattered to Wr[kb][row][32]:
//     dst(row,k) = (k>>5)*32768 + row*32 + (k&31)   (shorts)
// ---------------------------------------------------------------------------
__global__ __launch_bounds__(256) void convw_kernel(
    const float* __restrict__ w, unsigned short* __restrict__ o)
{
    int gid = blockIdx.x * 256 + threadIdx.x;
    int idx = gid * 4;                 // flat element index (row*512 + k)
    int row = idx >> 9;
    int k   = idx & 511;
    float4 v = *(const float4*)(w + idx);
    uint2 p;
    p.x = (unsigned)f2bf(v.x) | ((unsigned)f2bf(v.y) << 16);
    p.y = (unsigned)f2bf(v.z) | ((unsigned)f2bf(v.w) << 16);
    int dst = ((k >> 5) << 15) + (row << 5) + (k & 31);   // 4 k stay in one kb
    *(uint2*)(o + dst) = p;
}

// ---------------------------------------------------------------------------
// k2: c[n,d] = dot(static[n,:], Wc[d,:]) + bc[d]  via MFMA bf16. (unchanged)
// ---------------------------------------------------------------------------
__global__ __launch_bounds__(256) void city_kernel(
    const float* __restrict__ st,    // [2048,256]
    const float* __restrict__ Wc,    // [1024,256]
    const float* __restrict__ bc,    // [1024]
    unsigned short* __restrict__ cg) // bf16 [2048,1024]
{
    __shared__ __align__(16) unsigned short Sa[64 * 264];
    __shared__ __align__(16) unsigned short Sb[128 * 264];
    const int t  = threadIdx.x;
    const int n0 = blockIdx.x << 6;
    const int d0 = blockIdx.y << 7;

    #pragma unroll
    for (int i = 0; i < 16; ++i) {
        int idx = (i << 8) + t;
        int row = idx >> 6, kq = (idx & 63) << 2;
        float4 v = *(const float4*)(st + (size_t)(n0 + row) * 256 + kq);
        uint2 p;
        p.x = (unsigned)f2bf(v.x) | ((unsigned)f2bf(v.y) << 16);
        p.y = (unsigned)f2bf(v.z) | ((unsigned)f2bf(v.w) << 16);
        *(uint2*)(Sa + row * 264 + kq) = p;
    }
    #pragma unroll
    for (int i = 0; i < 32; ++i) {
        int idx = (i << 8) + t;
        int row = idx >> 6, kq = (idx & 63) << 2;
        float4 v = *(const float4*)(Wc + (size_t)(d0 + row) * 256 + kq);
        uint2 p;
        p.x = (unsigned)f2bf(v.x) | ((unsigned)f2bf(v.y) << 16);
        p.y = (unsigned)f2bf(v.z) | ((unsigned)f2bf(v.w) << 16);
        *(uint2*)(Sb + row * 264 + kq) = p;
    }
    __syncthreads();

    const int wv = t >> 6;
    const int cl = t & 15, q = (t >> 4) & 3;
    f32x4 acc[4][2];
    #pragma unroll
    for (int rt = 0; rt < 4; ++rt)
        #pragma unroll
        for (int ct = 0; ct < 2; ++ct) acc[rt][ct] = (f32x4)0.f;

    #pragma unroll
    for (int ks = 0; ks < 8; ++ks) {
        short8 a[4];
        #pragma unroll
        for (int rt = 0; rt < 4; ++rt)
            a[rt] = *(const short8*)(Sa + ((rt << 4) + cl) * 264 + (ks << 5) + (q << 3));
        #pragma unroll
        for (int ct = 0; ct < 2; ++ct) {
            short8 bf8 = *(const short8*)(Sb + ((wv << 5) + (ct << 4) + cl) * 264 + (ks << 5) + (q << 3));
            #pragma unroll
            for (int rt = 0; rt < 4; ++rt)
                acc[rt][ct] = __builtin_amdgcn_mfma_f32_16x16x32_bf16(a[rt], bf8, acc[rt][ct], 0, 0, 0);
        }
    }
    #pragma unroll
    for (int ct = 0; ct < 2; ++ct) {
        const int d = d0 + (wv << 5) + (ct << 4) + cl;
        const float bcv = bc[d];
        #pragma unroll
        for (int rt = 0; rt < 4; ++rt)
            #pragma unroll
            for (int rr = 0; rr < 4; ++rr) {
                const int row = (rt << 4) + (q << 2) + rr;
                cg[(size_t)(n0 + row) * 1024 + d] = f2bf(acc[rt][ct][rr] + bcv);
            }
    }
}

// ---------------------------------------------------------------------------
// k3: fused GEMM + leaky + gate + LayerNorm.  m97-structure double-buffer.
// 1024 threads = 16 waves. Wave w owns rows [0,64) x cols [w*64, w*64+64).
// LDS per step-buffer: A fp32 [64][32] (8KB, chunk c stored at c^(row&7)),
// B bf16 [1024][32] (64KB, linear Wr slab). Both staged by global_load_lds.
// ---------------------------------------------------------------------------
__global__ __launch_bounds__(1024, 4) void feat_kernel(
    const float* __restrict__ inp,          // [65536, 512] fp32
    const unsigned short* __restrict__ Wr,  // bf16 Wr[16][1024][32]
    const float* __restrict__ b_feat,       // [1024]
    const unsigned short* __restrict__ cg,  // bf16 [2048, 1024]
    const float* __restrict__ gamma,
    const float* __restrict__ beta,
    float* __restrict__ out)                // [65536, 1024] fp32
{
    __shared__ __align__(16) float          Ab[2][2048];   // 2 x 8 KB fp32
    __shared__ __align__(16) unsigned short Bb[2][32768];  // 2 x 64 KB bf16
    __shared__ float red1[1024];
    __shared__ float red2[1024];
    __shared__ float smu[64];
    __shared__ float srs[64];

    const int t    = threadIdx.x;
    const int lane = t & 63;
    const int w    = t >> 6;            // wave 0..15 = column strip
    const int cl   = lane & 15;
    const int q    = lane >> 4;
    const int m0   = blockIdx.x << 6;
    const int n0   = m0 & 2047;         // 2048 % 64 == 0: block never crosses b

    f32x4 acc[4][4];
    #pragma unroll
    for (int rt = 0; rt < 4; ++rt)
        #pragma unroll
        for (int ct = 0; ct < 4; ++ct) acc[rt][ct] = (f32x4)0.f;

    // ---- staging geometry ----
    // B: wave w stages slab chunks i = 4w..4w+3 (1 KB each, linear):
    //    lds = Bb[p] + i*512 shorts; global lane addr = Wr + kb*32768 + i*512 + lane*8
    // A: waves 0..7 stage rows 8w..8w+7 (one 1KB gll):
    //    lane L -> lds slot (row = 8w + L>>3, chunk L&7); global chunk (L&7)^(L>>3)
    const unsigned short* bgp = Wr + (size_t)(lane << 3);
    const int arow = (w << 3) + (lane >> 3);          // global A row within tile
    const int acg  = (lane & 7) ^ (lane >> 3);        // pre-swizzled global chunk
    const float* agp = inp + (size_t)(m0 + arow) * 512 + (acg << 2);

    // frag-read swizzle constants
    const int key = cl & 7;
    const int c0s = (((q << 1)) ^ key) << 2;          // float offset, lo chunk
    const int c1s = (((q << 1) | 1) ^ key) << 2;      // float offset, hi chunk

#define STAGE(pb, kb)                                                        \
    do {                                                                     \
        _Pragma("unroll")                                                    \
        for (int j_ = 0; j_ < 4; ++j_) {                                     \
            int i_ = (w << 2) + j_;                                          \
            LDS_ASYNC16(bgp + ((size_t)(kb) << 15) + (i_ << 9),              \
                        &Bb[pb][i_ << 9]);                                   \
        }                                                                    \
        if (w < 8)                                                           \
            LDS_ASYNC16(agp + ((kb) << 5), &Ab[pb][w << 8]);                 \
    } while (0)

    // ---- prologue ----
    STAGE(0, 0);
    __syncthreads();

    // ---- K-loop: 16 steps, double-buffered, one barrier per step ----
    #pragma unroll
    for (int ks = 0; ks < 16; ++ks) {
        const int p = ks & 1;
        if (ks < 15) STAGE(p ^ 1, ks + 1);

        short8 a[4];
        #pragma unroll
        for (int rt = 0; rt < 4; ++rt) {
            const float* abase = &Ab[p][((rt << 4) + cl) << 5];
            float4 lo = *(const float4*)(abase + c0s);
            float4 hi = *(const float4*)(abase + c1s);
            unsigned p0, p1, p2, p3;
            asm("v_cvt_pk_bf16_f32 %0, %1, %2" : "=v"(p0) : "v"(lo.x), "v"(lo.y));
            asm("v_cvt_pk_bf16_f32 %0, %1, %2" : "=v"(p1) : "v"(lo.z), "v"(lo.w));
            asm("v_cvt_pk_bf16_f32 %0, %1, %2" : "=v"(p2) : "v"(hi.x), "v"(hi.y));
            asm("v_cvt_pk_bf16_f32 %0, %1, %2" : "=v"(p3) : "v"(hi.z), "v"(hi.w));
            union { unsigned u[4]; short8 s; } cv;
            cv.u[0] = p0; cv.u[1] = p1; cv.u[2] = p2; cv.u[3] = p3;
            a[rt] = cv.s;
        }
        #pragma unroll
        for (int ct = 0; ct < 4; ++ct) {
            short8 bf8 = *(const short8*)(
                &Bb[p][(((w << 6) + (ct << 4) + cl) << 5) + (q << 3)]);
            #pragma unroll
            for (int rt = 0; rt < 4; ++rt)
                acc[rt][ct] = __builtin_amdgcn_mfma_f32_16x16x32_bf16(a[rt], bf8, acc[rt][ct], 0, 0, 0);
        }
        __syncthreads();
    }
#undef STAGE

    // ---- epilogue: bias + leaky + gate, LN stats, normalize, store ----
    float bfv[4];
    #pragma unroll
    for (int ct = 0; ct < 4; ++ct) bfv[ct] = b_feat[(w << 6) + (ct << 4) + cl];

    #pragma unroll
    for (int rt = 0; rt < 4; ++rt) {
        #pragma unroll
        for (int rr = 0; rr < 4; ++rr) {
            const int row = (rt << 4) + (q << 2) + rr;
            float s1 = 0.f, s2 = 0.f;
            #pragma unroll
            for (int ct = 0; ct < 4; ++ct) {
                const int d = (w << 6) + (ct << 4) + cl;
                float x = acc[rt][ct][rr] + bfv[ct];
                x = (x >= 0.f) ? x : 0.2f * x;
                x *= b2f(cg[(size_t)(n0 + row) * 1024 + d]);
                acc[rt][ct][rr] = x;
                s1 += x;
                s2 += x * x;
            }
            #pragma unroll
            for (int off = 1; off < 16; off <<= 1) {
                s1 += __shfl_xor(s1, off, 64);
                s2 += __shfl_xor(s2, off, 64);
            }
            if (cl == 0) {
                red1[(w << 6) + row] = s1;
                red2[(w << 6) + row] = s2;
            }
        }
    }
    __syncthreads();
    if (t < 64) {
        float a = 0.f, bb = 0.f;
        #pragma unroll
        for (int j = 0; j < 16; ++j) { a += red1[(j << 6) + t]; bb += red2[(j << 6) + t]; }
        const float mu  = a * (1.0f / 1024.0f);
        const float var = bb * (1.0f / 1024.0f) - mu * mu;
        smu[t] = mu;
        srs[t] = rsqrtf(var + 1e-5f);
    }
    __syncthreads();

    #pragma unroll
    for (int ct = 0; ct < 4; ++ct) {
        const int d = (w << 6) + (ct << 4) + cl;
        const float g = gamma[d], be = beta[d];
        #pragma unroll
        for (int rt = 0; rt < 4; ++rt) {
            #pragma unroll
            for (int rr = 0; rr < 4; ++rr) {
                const int row = (rt << 4) + (q << 2) + rr;
                __builtin_nontemporal_store(
                    (acc[rt][ct][rr] - smu[row]) * srs[row] * g + be,
                    &out[(size_t)(m0 + row) * 1024 + d]);
            }
        }
    }
}

// ---------------------------------------------------------------------------
extern "C" void kernel_launch(void* const* d_in, const int* in_sizes, int n_in,
                              void* d_out, int out_size, void* d_ws, size_t ws_size,
                              hipStream_t stream) {
    const float* inp   = (const float*)d_in[0];   // [32,2048,512]
    const float* st    = (const float*)d_in[1];   // [2048,256]
    const float* Wf    = (const float*)d_in[2];   // [1024,512]
    const float* bfeat = (const float*)d_in[3];   // [1024]
    const float* Wc    = (const float*)d_in[4];   // [1024,256]
    const float* bc    = (const float*)d_in[5];   // [1024]
    const float* gamma = (const float*)d_in[6];   // [1024]
    const float* beta  = (const float*)d_in[7];   // [1024]
    float* out = (float*)d_out;

    unsigned short* wsWr = (unsigned short*)d_ws;                      // 1 MB bf16 Wr
    unsigned short* wsC  = (unsigned short*)((char*)d_ws + (1 << 20)); // 4 MB bf16 c

    convw_kernel<<<512, 256, 0, stream>>>(Wf, wsWr);
    city_kernel<<<dim3(32, 8), 256, 0, stream>>>(st, Wc, bc, wsC);
    feat_kernel<<<1024, 1024, 0, stream>>>(inp, wsWr, bfeat, wsC, gamma, beta, out);
}